// Round 4
// baseline (1043.399 us; speedup 1.0000x reference)
//
#include <hip/hip_runtime.h>

// Flashback forward. Key analytic facts used:
//  * sim cancels in w_ii/sum_w  -> Wp/bp/pref_emb/x_proj/p_proj are dead code.
//  * out_w[i] = out[i] * r[i,u],  r = (f_t(0)f_s(ds_ii)+1e-10) / sum_{j<=i}(f_t f_s + 1e-10)
//  * y = [out_w | p_u] @ W_fc^T + b_fc   (M=16384, N=10000, K=256) -> bf16 MFMA GEMM
//  * h_out = final RNN hidden state (exact fp32 path)

#define S_LEN  64
#define NUSERS 256
#define HDIM   128
#define NLOC   10000
#define K2H    256
#define MROWS  16384      // S*U
#define NPAD   10112      // 79*128 padded N for the GEMM B matrix

typedef __attribute__((ext_vector_type(8))) short bf16x8;
typedef __attribute__((ext_vector_type(4))) float f32x4;

typedef __attribute__((address_space(1))) void gvoid_t;
typedef __attribute__((address_space(3))) void lvoid_t;

__device__ __forceinline__ unsigned short f2bf(float f) {
  unsigned int u = __float_as_uint(f);
  u += 0x7fffu + ((u >> 16) & 1u);   // RNE
  return (unsigned short)(u >> 16);
}

// ---- K1: r[i,u] = w_ii / sum_{j<=i} w_ij  (sim factor cancels) ----
__global__ __launch_bounds__(64) void qratio_kernel(
    const float* __restrict__ t, const float* __restrict__ s,
    float* __restrict__ r) {
  int u = blockIdx.x;
  int i = threadIdx.x;
  __shared__ float ts[64], sx[64], sy[64];
  ts[i] = t[i * NUSERS + u];
  sx[i] = s[(i * NUSERS + u) * 2 + 0];
  sy[i] = s[(i * NUSERS + u) * 2 + 1];
  __syncthreads();
  float ti = ts[i], xi = sx[i], yi = sy[i];
  float q = 0.0f, wii = 1.0f;
  for (int j = 0; j <= i; ++j) {
    float dt = ti - ts[j];                       // >= 0 (t sorted along seq)
    float dx = xi - sx[j], dy = yi - sy[j];
    float dss = sqrtf(dx * dx + dy * dy + 1e-12f);
    float ft = (cosf(dt * 7.2722052166430395e-05f) + 1.0f) * 0.5f *
               expf(dt * (-0.1f / 86400.0f));
    float fs = expf(-100.0f * dss);
    float w = ft * fs + 1e-10f;
    q += w;
    if (j == i) wii = w;                         // diagonal term, bit-identical
  }
  r[i * NUSERS + u] = wii / q;
}

// ---- K2: W_fc (10000x256 f32) -> bf16, zero-padded to 10112 rows ----
__global__ __launch_bounds__(256) void convert_b_kernel(
    const float* __restrict__ W_fc, unsigned short* __restrict__ Bb) {
  int idx = blockIdx.x * 256 + threadIdx.x;      // 0 .. 647167 (NPAD*K2H/4)
  int e = idx << 2;
  int row = e >> 8;                              // / 256
  float4 v = make_float4(0.f, 0.f, 0.f, 0.f);
  if (row < NLOC) v = *(const float4*)&W_fc[e];
  ushort4 o;
  o.x = f2bf(v.x); o.y = f2bf(v.y); o.z = f2bf(v.z); o.w = f2bf(v.w);
  *(ushort4*)&Bb[e] = o;
}

// ---- K3: tanh-RNN, one user per block (one CU), W staged in LDS ----
// Writes A matrix rows: [ bf16(h_i * r_i) | bf16(p_u) ]  and h_out (fp32).
__global__ __launch_bounds__(128) void rnn_kernel(
    const int* __restrict__ x, const float* __restrict__ h0,
    const int* __restrict__ active_user,
    const float* __restrict__ enc_emb, const float* __restrict__ user_emb,
    const float* __restrict__ W_ih, const float* __restrict__ b_ih,
    const float* __restrict__ W_hh, const float* __restrict__ b_hh,
    const float* __restrict__ rws, unsigned short* __restrict__ Abf,
    float* __restrict__ hout) {
  const int u = blockIdx.x, tid = threadIdx.x;
  // stride 132 floats: 16B-aligned rows; within a 16-lane phase the b128
  // start banks are 2-way aliased only (free per m136).
  __shared__ float Wi[128 * 132];
  __shared__ float Wh[128 * 132];
  __shared__ float xe[128];
  __shared__ float hb[128];
  #pragma unroll 4
  for (int e = tid; e < 4096; e += 128) {
    int row = e >> 5, c4 = (e & 31) << 2;
    *(float4*)&Wi[row * 132 + c4] = *(const float4*)&W_ih[(row << 7) + c4];
    *(float4*)&Wh[row * 132 + c4] = *(const float4*)&W_hh[(row << 7) + c4];
  }
  unsigned short pub = f2bf(user_emb[active_user[u] * HDIM + tid]);
  float bi = b_ih[tid] + b_hh[tid];
  float hn = h0[u * HDIM + tid];
  for (int i = 0; i < S_LEN; ++i) {
    float xv = enc_emb[x[i * NUSERS + u] * HDIM + tid];
    float rw = rws[i * NUSERS + u];
    __syncthreads();                 // prior iteration's LDS reads complete
    xe[tid] = xv;
    hb[tid] = hn;
    __syncthreads();                 // xe/hb (and preamble W) visible
    float a0 = 0.f, a1 = 0.f, a2 = 0.f, a3 = 0.f;
    #pragma unroll
    for (int k4 = 0; k4 < 32; ++k4) {
      float4 wa = *(const float4*)&Wi[tid * 132 + (k4 << 2)];
      float4 xq = *(const float4*)&xe[k4 << 2];
      float4 wb = *(const float4*)&Wh[tid * 132 + (k4 << 2)];
      float4 hq = *(const float4*)&hb[k4 << 2];
      a0 += wa.x * xq.x + wa.y * xq.y;
      a1 += wa.z * xq.z + wa.w * xq.w;
      a2 += wb.x * hq.x + wb.y * hq.y;
      a3 += wb.z * hq.z + wb.w * hq.w;
    }
    hn = tanhf(bi + ((a0 + a1) + (a2 + a3)));
    int arow = (i * NUSERS + u) * K2H;
    Abf[arow + tid] = f2bf(hn * rw);
    Abf[arow + HDIM + tid] = pub;
  }
  hout[u * HDIM + tid] = hn;
}

// ---- K4: bf16 MFMA GEMM, 128x128 tile, BK=32, global_load_lds staging ----
// A: (16384 x 256) bf16 row-major, B: (10112 x 256) bf16 row-major ("B^T" GEMM)
// LDS tiles stored with block-index XOR swizzle: phys blk = blk ^ ((row>>1)&3)
// (applied on the per-lane GLOBAL source address; LDS dest stays linear —
// both-sides-or-neither, rule #21).
__global__ __launch_bounds__(256) void gemm_kernel(
    const unsigned short* __restrict__ A, const unsigned short* __restrict__ B,
    const float* __restrict__ b_fc, float* __restrict__ Y) {
  __shared__ char smem[32768];       // 2 buffers x (A 8KB + B 8KB)
  int tid = threadIdx.x;
  int lane = tid & 63, wave = tid >> 6;
  int wr = wave >> 1, wc = wave & 1;

  // XCD-aware swizzle: grid = 128*79 = 10112, divisible by 8 -> bijective
  int bid = blockIdx.x;
  int cpx = (128 * 79) >> 3;
  int swz = (bid & 7) * cpx + (bid >> 3);
  int mt = swz & 127;                // M tile 0..127
  int nt = swz >> 7;                 // N tile 0..78
  const char* gA = (const char*)A + mt * 128 * 512;   // row stride 512 B
  const char* gB = (const char*)B + nt * 128 * 512;

  // per-thread staging source offsets (2 rounds of 256 threads x 16 B per tile)
  int e0 = tid, e1 = 256 + tid;
  int row0 = e0 >> 2, row1 = e1 >> 2;
  int ga0 = row0 * 512 + (((e0 & 3) ^ ((row0 >> 1) & 3)) << 4);
  int ga1 = row1 * 512 + (((e1 & 3) ^ ((row1 >> 1) & 3)) << 4);
  int ldsw = wave << 10;             // wave-uniform LDS base offset

#define STAGE(bufbase, goff) do {                                               \
    __builtin_amdgcn_global_load_lds((gvoid_t*)(gA + (goff) + ga0),             \
        (lvoid_t*)((bufbase) + ldsw), 16, 0, 0);                                \
    __builtin_amdgcn_global_load_lds((gvoid_t*)(gA + (goff) + ga1),             \
        (lvoid_t*)((bufbase) + 4096 + ldsw), 16, 0, 0);                         \
    __builtin_amdgcn_global_load_lds((gvoid_t*)(gB + (goff) + ga0),             \
        (lvoid_t*)((bufbase) + 8192 + ldsw), 16, 0, 0);                         \
    __builtin_amdgcn_global_load_lds((gvoid_t*)(gB + (goff) + ga1),             \
        (lvoid_t*)((bufbase) + 12288 + ldsw), 16, 0, 0);                        \
  } while (0)

  f32x4 acc[4][4];
  #pragma unroll
  for (int i = 0; i < 4; ++i)
    #pragma unroll
    for (int j = 0; j < 4; ++j)
      acc[i][j] = (f32x4){0.f, 0.f, 0.f, 0.f};

  STAGE(smem, 0);
  __syncthreads();

  for (int kt = 0; kt < 8; ++kt) {
    char* cb = smem + ((kt & 1) << 14);
    if (kt < 7) {
      char* nb = smem + (((kt + 1) & 1) << 14);
      STAGE(nb, (kt + 1) << 6);
    }
    bf16x8 af[4], bfr[4];
    int l15 = lane & 15, blkL = lane >> 4;
    #pragma unroll
    for (int tt = 0; tt < 4; ++tt) {
      int rowA = (wr << 6) + (tt << 4) + l15;
      af[tt] = *(const bf16x8*)(cb + rowA * 64 +
                                ((blkL ^ ((rowA >> 1) & 3)) << 4));
      int rowB = (wc << 6) + (tt << 4) + l15;
      bfr[tt] = *(const bf16x8*)(cb + 8192 + rowB * 64 +
                                 ((blkL ^ ((rowB >> 1) & 3)) << 4));
    }
    #pragma unroll
    for (int i = 0; i < 4; ++i)
      #pragma unroll
      for (int j = 0; j < 4; ++j)
        acc[i][j] = __builtin_amdgcn_mfma_f32_16x16x32_bf16(af[i], bfr[j],
                                                            acc[i][j], 0, 0, 0);
    __syncthreads();
  }
#undef STAGE

  // epilogue: D lane map col = lane&15, row = (lane>>4)*4 + j
  int colq = (nt << 7) + (wc << 6) + (lane & 15);
  int rowq = (mt << 7) + (wr << 6) + ((lane >> 4) << 2);
  #pragma unroll
  for (int j = 0; j < 4; ++j) {
    int col = colq + (j << 4);
    if (col < NLOC) {
      float bias = b_fc[col];
      #pragma unroll
      for (int i = 0; i < 4; ++i) {
        int rw = rowq + (i << 4);
        f32x4 c = acc[i][j];
        Y[(rw + 0) * NLOC + col] = c[0] + bias;
        Y[(rw + 1) * NLOC + col] = c[1] + bias;
        Y[(rw + 2) * NLOC + col] = c[2] + bias;
        Y[(rw + 3) * NLOC + col] = c[3] + bias;
      }
    }
  }
}

extern "C" void kernel_launch(void* const* d_in, const int* in_sizes, int n_in,
                              void* d_out, int out_size, void* d_ws, size_t ws_size,
                              hipStream_t stream) {
  const int*   x           = (const int*)d_in[0];
  const float* t           = (const float*)d_in[1];
  const float* s           = (const float*)d_in[2];
  const float* h0          = (const float*)d_in[5];
  const int*   active_user = (const int*)d_in[6];
  const float* enc_emb     = (const float*)d_in[7];
  const float* user_emb    = (const float*)d_in[8];
  const float* W_ih        = (const float*)d_in[10];
  const float* b_ih        = (const float*)d_in[11];
  const float* W_hh        = (const float*)d_in[12];
  const float* b_hh        = (const float*)d_in[13];
  const float* W_fc        = (const float*)d_in[16];
  const float* b_fc        = (const float*)d_in[17];

  float* Y    = (float*)d_out;
  float* hout = Y + (size_t)MROWS * NLOC;        // h_out after y

  char* ws = (char*)d_ws;
  float*          rws = (float*)ws;                          // 64 KB
  unsigned short* Abf = (unsigned short*)(ws + 65536);       // 8.0 MB
  unsigned short* Bb  = (unsigned short*)(ws + 8454144);     // 4.9 MB

  qratio_kernel<<<NUSERS, 64, 0, stream>>>(t, s, rws);
  convert_b_kernel<<<(NPAD * K2H / 4) / 256, 256, 0, stream>>>(W_fc, Bb);
  rnn_kernel<<<NUSERS, 128, 0, stream>>>(x, h0, active_user, enc_emb, user_emb,
                                         W_ih, b_ih, W_hh, b_hh, rws, Abf, hout);
  gemm_kernel<<<128 * 79, 256, 0, stream>>>(Abf, Bb, b_fc, Y);
}